// Round 8
// baseline (234.150 us; speedup 1.0000x reference)
//
#include <hip/hip_runtime.h>
#include <math.h>

#define SEQ  4096
#define DIN  1024
#define DOUT 1024

typedef __attribute__((ext_vector_type(16))) float f32x16;
typedef __attribute__((ext_vector_type(8))) short short8;

// ---------------------------------------------------------------------------
// bf16 helpers (RTN)
// ---------------------------------------------------------------------------
__device__ inline short bf16_rtn(float f) {
  unsigned u = __builtin_bit_cast(unsigned, f);
  unsigned r = (u + 0x7FFFu + ((u >> 16) & 1u)) >> 16;
  return (short)r;
}
__device__ inline float bf16_to_f(short h) {
  unsigned u = ((unsigned)(unsigned short)h) << 16;
  return __builtin_bit_cast(float, u);
}

// async 16B global -> LDS (wave-uniform LDS base + lane*16)
typedef const unsigned __attribute__((address_space(1)))* gas_u32p;
typedef unsigned __attribute__((address_space(3)))* las_u32p;
__device__ inline void gll16(const void* g, void* l) {
  __builtin_amdgcn_global_load_lds((gas_u32p)g, (las_u32p)l, 16, 0, 0);
}

// ---------------------------------------------------------------------------
// bf16 NT GEMM core, 32x32x16 MFMA, fp32 accum:  acc = A @ B^T
// A : [M, K] bf16 bits, row stride sA.  B : [N, K] bf16 bits, row stride sB.
// BM=128, BN in {64,128}, BK=64, 256 threads = 4 waves (2x2 of 64 x BN/2).
// 32x32x16 vs 16x16x32: same FLOPs in ~17% fewer MFMA-pipe cycles (m119:
// 2495 vs 2176 TF) and half the MFMA instruction issues; ds_read count
// unchanged.  A/B operand layout: elem[m = lane&31][k = (lane>>5)*8 + j].
// C/D layout (m74/m101): col = lane&31, row = (reg&3)+8*(reg>>2)+4*(lane>>5).
// Swizzle: chunk c of row r stored at slot c ^ (r & 7).  Group-major block
// swizzle (GROUP_M=8) keeps the generation working set inside per-XCD L2s.
// Epilogues:
//   EPI=0: Cd[idx] = acc*alpha                        (fp32 out / partial)
//   EPI=2: Cb[idx] = bf16(acc*alpha)                  (bf16 out: q/k/v)
//   EPI=3: Cb[idx] = bf16(exp(acc*alpha)) + fused row-sum atomicAdd to Lw
// ---------------------------------------------------------------------------
template <int EPI, int BN, int BK>
__device__ __forceinline__ void gemm_core(
    const short* __restrict__ A, int sA,
    const short* __restrict__ B, int sB,
    float* __restrict__ Cd, short* __restrict__ Cb, float* __restrict__ Lw,
    int sC, int Klen, float alpha, int nbx, int nby, int id) {
  constexpr int JT  = BN / 64;            // wave-local 32-wide n-subtiles
  constexpr int CPR = BK / 8;             // 16B chunks per LDS row
  constexpr int CM  = CPR - 1;
  __shared__ __align__(16) short lA[128 * BK];
  __shared__ __align__(16) short lB[BN * BK];

  const int tid = threadIdx.x;
  const int wave = tid >> 6, lane = tid & 63;
  const int l32 = lane & 31, h = lane >> 5;

  // ---- group-major swizzle: walk M within groups of 8 before advancing N ----
  const int GRP = 8;
  const int width = GRP * nbx;
  const int group = id / width;
  const int first_y = group * GRP;
  const int gsz = (nby - first_y < GRP) ? (nby - first_y) : GRP;
  const int by = first_y + (id % gsz);
  const int bx = (id % width) / gsz;

  const int m0 = by * 128, n0 = bx * BN;
  const int mw = (wave >> 1) * 64, nw = (wave & 1) * (BN / 2);

  f32x16 acc[2][JT] = {};

  for (int k0 = 0; k0 < Klen; k0 += BK) {
    __syncthreads();
#pragma unroll
    for (int w = 0; w < (128 * CPR) / 256; ++w) {   // stage A tile
      const int s = tid + 256 * w;
      const int r = s / CPR;
      const int c = (s & CM) ^ (r & CM);
      gll16(A + (size_t)(m0 + r) * sA + k0 + c * 8, lA + s * 8);
    }
#pragma unroll
    for (int w = 0; w < (BN * CPR) / 256; ++w) {    // stage B tile
      const int s = tid + 256 * w;
      const int r = s / CPR;
      const int c = (s & CM) ^ (r & CM);
      gll16(B + (size_t)(n0 + r) * sB + k0 + c * 8, lB + s * 8);
    }
    __syncthreads();

#pragma unroll
    for (int ks = 0; ks < BK / 16; ++ks) {          // K16 steps
      short8 af[2], bfr[JT];
#pragma unroll
      for (int i = 0; i < 2; ++i) {
        const int ra = mw + i * 32 + l32;
        const int cx = ((ks << 1) | h) ^ (ra & CM);
        af[i] = *(const short8*)(lA + (ra * CPR + cx) * 8);
      }
#pragma unroll
      for (int j = 0; j < JT; ++j) {
        const int rb = nw + j * 32 + l32;
        const int cx = ((ks << 1) | h) ^ (rb & CM);
        bfr[j] = *(const short8*)(lB + (rb * CPR + cx) * 8);
      }
#pragma unroll
      for (int i = 0; i < 2; ++i)
#pragma unroll
        for (int j = 0; j < JT; ++j)
          acc[i][j] = __builtin_amdgcn_mfma_f32_32x32x16_bf16(af[i], bfr[j], acc[i][j], 0, 0, 0);
    }
  }

  // epilogue: C/D col = l32, row = (reg&3) + 8*(reg>>2) + 4*h
#pragma unroll
  for (int i = 0; i < 2; ++i)
#pragma unroll
    for (int reg = 0; reg < 16; ++reg) {
      const int row = m0 + mw + i * 32 + (reg & 3) + 8 * (reg >> 2) + 4 * h;
      float rsum = 0.f;
#pragma unroll
      for (int j = 0; j < JT; ++j) {
        const int col = n0 + nw + j * 32 + l32;
        const size_t idx = (size_t)row * sC + col;
        const float v = acc[i][j][reg];
        if (EPI == 0) Cd[idx] = v * alpha;
        if (EPI == 2) Cb[idx] = bf16_rtn(v * alpha);
        if (EPI == 3) {
          const short e = bf16_rtn(__expf(fminf(v * alpha, 80.f)));
          Cb[idx] = e;
          rsum += bf16_to_f(e);  // sum the ROUNDED value (consistent normalize)
        }
      }
      if (EPI == 3) {
        // reduce across the 32 col-lanes of this row (halves stay separate)
#pragma unroll
        for (int off = 1; off < 32; off <<= 1) rsum += __shfl_xor(rsum, off, 64);
        if (l32 == 0) atomicAdd(&Lw[row], rsum);
      }
    }
}

// generic wrapper (split-K via blockIdx.z: z=0 -> C, z=1 -> C2)
template <int EPI, int BN, int BK>
__global__ __launch_bounds__(256, 2) void gemm32(
    const short* __restrict__ A, int sA,
    const short* __restrict__ B, int sB,
    float* __restrict__ C, float* __restrict__ C2, short* __restrict__ Cb,
    float* __restrict__ Lw, int sC, int Ksplit, float alpha) {
  const short* Ab = A + (size_t)blockIdx.z * Ksplit;
  const short* Bb = B + (size_t)blockIdx.z * Ksplit;
  float* Cd = blockIdx.z ? C2 : C;
  const int id = blockIdx.y * gridDim.x + blockIdx.x;
  gemm_core<EPI, BN, BK>(Ab, sA, Bb, sB, Cd, Cb, Lw, sC, Ksplit, alpha,
                         gridDim.x, gridDim.y, id);
}

// merged projections: blocks [0,1024) -> q|k = x @ [Wq|Wk]^T,
//                     blocks [1024,1536) -> v^T = Wv^T @ x^T
__global__ __launch_bounds__(256, 2) void proj_both(
    const short* __restrict__ xh, const short* __restrict__ Wt,
    const short* __restrict__ Wtv,
    short* __restrict__ qk, short* __restrict__ vt) {
  const int id = blockIdx.x;
  if (id < 1024) {
    gemm_core<2, 64, 64>(xh, DIN, Wt, DIN, nullptr, qk, nullptr,
                         2048, DIN, 1.f, 32, 32, id);
  } else {
    gemm_core<2, 64, 64>(Wtv, DIN, xh, DIN, nullptr, vt, nullptr,
                         SEQ, DIN, 1.f, 64, 8, id - 1024);
  }
}

// ---------------------------------------------------------------------------
// Fused prep (one launch): x cast, 3 weight transpose+casts, lsum zero.
// ---------------------------------------------------------------------------
__global__ __launch_bounds__(256) void prep_fused(
    const float* __restrict__ x, short* __restrict__ xh,
    const float* __restrict__ Wq, const float* __restrict__ Wk,
    const float* __restrict__ Wv,
    short* __restrict__ Wt, short* __restrict__ Wtv,
    float* __restrict__ lsum) {
  __shared__ float t[32][33];
  const int b = blockIdx.x;
  if (b < 4096) {
    const int i = b * 256 + threadIdx.x;
    const float4 f = ((const float4*)x)[i];
    short4 h;
    h.x = bf16_rtn(f.x);
    h.y = bf16_rtn(f.y);
    h.z = bf16_rtn(f.z);
    h.w = bf16_rtn(f.w);
    ((short4*)xh)[i] = h;
  } else if (b < 7168) {
    const int tb = b - 4096;
    const int which = tb >> 10;          // 0=Wq 1=Wk 2=Wv
    const int b2 = tb & 1023;
    const float* W = (which == 0) ? Wq : (which == 1) ? Wk : Wv;
    short* T = (which == 0) ? Wt : (which == 1) ? (Wt + DIN * DOUT) : Wtv;
    const int bx = (b2 & 31) * 32;       // dout base
    const int by = (b2 >> 5) * 32;       // din base
    const int tx = threadIdx.x & 31, ty = threadIdx.x >> 5;  // ty 0..7
#pragma unroll
    for (int j = 0; j < 4; ++j)
      t[ty + j * 8][tx] = W[(size_t)(by + ty + j * 8) * DOUT + bx + tx];
    __syncthreads();
#pragma unroll
    for (int j = 0; j < 4; ++j) {
      const float v = t[tx][ty + j * 8];  // = W[by+tx][bx+ty+j*8]
      T[(size_t)(bx + ty + j * 8) * DIN + by + tx] = bf16_rtn(v);
    }
  } else {
    const int i = (b - 7168) * 256 + threadIdx.x;
    if (i < SEQ) lsum[i] = 0.f;
  }
}

// ---------------------------------------------------------------------------
// Split-K combine + softmax normalize: out = (out + part) / lsum[row]
// ---------------------------------------------------------------------------
__global__ __launch_bounds__(256) void combine_div(float* __restrict__ out,
                                                   const float* __restrict__ part,
                                                   const float* __restrict__ lsum) {
  const int i = blockIdx.x * 256 + threadIdx.x;  // over 1M float4
  float4 a = ((const float4*)out)[i];
  const float4 b = ((const float4*)part)[i];
  const float inv = 1.0f / lsum[(i * 4) >> 10];  // row = idx/1024
  a.x = (a.x + b.x) * inv;
  a.y = (a.y + b.y) * inv;
  a.z = (a.z + b.z) * inv;
  a.w = (a.w + b.w) * inv;
  ((float4*)out)[i] = a;
}

// ===========================================================================
// Fallback fp32 path (round-1 kernels) for small workspaces
// ===========================================================================
template <bool BT>
__global__ __launch_bounds__(256) void gemm_f32(const float* __restrict__ A,
                                                const float* __restrict__ B,
                                                float* __restrict__ C,
                                                int M, int N, int K, float alpha) {
  __shared__ __align__(16) float As[16][68];
  __shared__ __align__(16) float Bs[16][68];
  const int tid = threadIdx.x;
  const int tx = tid & 15, ty = tid >> 4;
  const int m0 = blockIdx.y * 64, n0 = blockIdx.x * 64;
  float acc[4][4] = {};
  for (int k0 = 0; k0 < K; k0 += 16) {
    {
      const int r = tid >> 2, j4 = tid & 3;
      const float4 av = *(const float4*)&A[(size_t)(m0 + r) * K + k0 + j4 * 4];
      As[j4 * 4 + 0][r] = av.x; As[j4 * 4 + 1][r] = av.y;
      As[j4 * 4 + 2][r] = av.z; As[j4 * 4 + 3][r] = av.w;
    }
    if (BT) {
      const int n = tid >> 2, j4 = tid & 3;
      const float4 bv = *(const float4*)&B[(size_t)(n0 + n) * K + k0 + j4 * 4];
      Bs[j4 * 4 + 0][n] = bv.x; Bs[j4 * 4 + 1][n] = bv.y;
      Bs[j4 * 4 + 2][n] = bv.z; Bs[j4 * 4 + 3][n] = bv.w;
    } else {
      const int kr = tid >> 4, n4 = tid & 15;
      *(float4*)&Bs[kr][n4 * 4] = *(const float4*)&B[(size_t)(k0 + kr) * N + n0 + n4 * 4];
    }
    __syncthreads();
#pragma unroll
    for (int kk = 0; kk < 16; ++kk) {
      const float4 a4 = *(const float4*)&As[kk][ty * 4];
      const float4 b4 = *(const float4*)&Bs[kk][tx * 4];
      const float a[4] = {a4.x, a4.y, a4.z, a4.w};
      const float b[4] = {b4.x, b4.y, b4.z, b4.w};
#pragma unroll
      for (int i = 0; i < 4; ++i)
#pragma unroll
        for (int j = 0; j < 4; ++j) acc[i][j] += a[i] * b[j];
    }
    __syncthreads();
  }
#pragma unroll
  for (int i = 0; i < 4; ++i) {
    const size_t m = m0 + ty * 4 + i;
#pragma unroll
    for (int j = 0; j < 4; ++j) C[m * N + n0 + tx * 4 + j] = alpha * acc[i][j];
  }
}

__global__ __launch_bounds__(256) void softmax_rows(float* __restrict__ S, int N) {
  float* p = S + (size_t)blockIdx.x * N;
  const int tid = threadIdx.x, lane = tid & 63, wave = tid >> 6;
  __shared__ float red[4];
  float m = -1e30f;
  for (int j = tid; j < N; j += 256) m = fmaxf(m, p[j]);
#pragma unroll
  for (int off = 32; off > 0; off >>= 1) m = fmaxf(m, __shfl_xor(m, off, 64));
  if (lane == 0) red[wave] = m;
  __syncthreads();
  m = fmaxf(fmaxf(red[0], red[1]), fmaxf(red[2], red[3]));
  __syncthreads();
  float s = 0.f;
  for (int j = tid; j < N; j += 256) {
    const float e = __expf(p[j] - m);
    p[j] = e;
    s += e;
  }
#pragma unroll
  for (int off = 32; off > 0; off >>= 1) s += __shfl_xor(s, off, 64);
  if (lane == 0) red[wave] = s;
  __syncthreads();
  s = red[0] + red[1] + red[2] + red[3];
  const float inv = 1.0f / s;
  for (int j = tid; j < N; j += 256) p[j] *= inv;
}

// ===========================================================================
// Host launch
// ===========================================================================
extern "C" void kernel_launch(void* const* d_in, const int* in_sizes, int n_in,
                              void* d_out, int out_size, void* d_ws, size_t ws_size,
                              hipStream_t stream) {
  const float* x  = (const float*)d_in[0];
  const float* Wq = (const float*)d_in[1];
  const float* Wk = (const float*)d_in[2];
  const float* Wv = (const float*)d_in[3];
  float* out = (float*)d_out;

  const size_t MB = 1ull << 20;
  const dim3 blk(256);

  if (ws_size >= 72 * MB) {
    // ---- pure-bf16 32x32-MFMA path ----
    char* ws = (char*)d_ws;
    short* xh   = (short*)ws;                  // [4096, 1024]  8 MB (dead after projections)
    short* Wt   = (short*)(ws + 8 * MB);       // [2048, 1024]  4 MB (Wq^T|Wk^T)
    short* Wtv  = (short*)(ws + 12 * MB);      // [1024, 1024]  2 MB (Wv^T)
    short* qk   = (short*)(ws + 14 * MB);      // [4096, 2048] 16 MB (q|k; dead after S)
    short* vt   = (short*)(ws + 30 * MB);      // [1024, 4096]  8 MB (v^T)
    short* E    = (short*)(ws + 38 * MB);      // [4096, 4096] 32 MB exp(s/32)
    float* lsum = (float*)(ws + 70 * MB);      // [4096] row sums
    float* part = (float*)ws;                  // [4096, 1024] 16 MB PV z=1 partial
                                               // (overlays dead xh/Wt/Wtv/qk-head)

    // 1. prep: x cast + 3 weight transposes + lsum zero  (one launch)
    prep_fused<<<dim3(7184), blk, 0, stream>>>(x, xh, Wq, Wk, Wv, Wt, Wtv, lsum);

    // 2. both projections in one dispatch (1536 blocks)
    proj_both<<<dim3(1536), blk, 0, stream>>>(xh, Wt, Wtv, qk, vt);

    // 3. E = exp(q @ k^T / 32) (bf16) + fused row sums -> lsum (atomicAdd)
    gemm32<3, 128, 64><<<dim3(SEQ / 128, SEQ / 128, 1), blk, 0, stream>>>(
        qk, 2048, qk + 1024, 2048, nullptr, nullptr, E, lsum, SEQ, DIN, 0.03125f);

    // 4. PV split-K=2: z=0 -> out (raw), z=1 -> part. grid 1024 = 4 blocks/CU
    gemm32<0, 64, 64><<<dim3(DOUT / 64, SEQ / 128, 2), blk, 0, stream>>>(
        E, SEQ, vt, SEQ, out, part, nullptr, nullptr, DOUT, SEQ / 2, 1.f);

    // 5. out = (out + part) / lsum[row]
    combine_div<<<dim3(SEQ * DOUT / 4 / 256), blk, 0, stream>>>(out, part, lsum);
  } else {
    // ---- fp32 fallback (round-1 path) ----
    float* q = (float*)d_ws;
    float* k = q + (size_t)SEQ * DOUT;
    float* v = k + (size_t)SEQ * DOUT;
    float* S = v + (size_t)SEQ * DOUT;
    const size_t base_bytes = (size_t)3 * SEQ * DOUT * sizeof(float);
    size_t avail = (ws_size > base_bytes) ? ws_size - base_bytes : 0;
    int panel = (int)(avail / ((size_t)SEQ * sizeof(float)));
    panel = (panel / 64) * 64;
    if (panel > SEQ) panel = SEQ;
    if (panel < 64) panel = 64;
    const float scale = 0.03125f;
    gemm_f32<false><<<dim3(DOUT / 64, SEQ / 64), blk, 0, stream>>>(x, Wq, q, SEQ, DOUT, DIN, 1.f);
    gemm_f32<false><<<dim3(DOUT / 64, SEQ / 64), blk, 0, stream>>>(x, Wk, k, SEQ, DOUT, DIN, 1.f);
    gemm_f32<false><<<dim3(DOUT / 64, SEQ / 64), blk, 0, stream>>>(x, Wv, v, SEQ, DOUT, DIN, 1.f);
    for (int r0 = 0; r0 < SEQ; r0 += panel) {
      const int pm = (SEQ - r0 < panel) ? (SEQ - r0) : panel;
      gemm_f32<true><<<dim3(SEQ / 64, pm / 64), blk, 0, stream>>>(
          q + (size_t)r0 * DOUT, k, S, pm, SEQ, DOUT, scale);
      softmax_rows<<<dim3(pm), blk, 0, stream>>>(S, SEQ);
      gemm_f32<false><<<dim3(DOUT / 64, pm / 64), blk, 0, stream>>>(
          S, v, out + (size_t)r0 * DOUT, pm, DOUT, SEQ, 1.f);
    }
  }
}